// Round 18
// baseline (140.113 us; speedup 1.0000x reference)
//
#include <hip/hip_runtime.h>

// B=4, C=256, N=4096 attention modulation.
// out[b,c,i] = newL[b,i]*src[b,c,i] + newB[b,i],
// newL[b,i] = sum_j softmax_j(E)*oldL[j], E = src_i . ref_j over C.
//
// R30 == R28 (session-best 138.56us), locked in after R29 confirmed the
// plateau (prep widening traded 8->4 blocks/CU occupancy for
// amortization, net null). Final structure:
//  - k_prep: 8 fused z-slices, 64x64 tiles (8 blocks/CU): src/ref
//    transpose -> fp16 MFMA fragments + 1x1-conv partials fused into the
//    ref slices' already-loaded LDS tiles (non-atomic, per-c-group).
//  - k_fin: oldL/oldB = sum of 4 partials + bias (float4, 16 blocks).
//  - k_flash: the blessed loop (verified local optimum, 27-31% MfmaUtil):
//    JSLICE=4 / NT=32 / grid 256 = 1 block/CU; 2x16KB syncthreads dbuf
//    via global_load_lds; T15 dual-acc finish interleave; per-tile
//    GLOBAL lam/bet from finalized oldL (LDS-lam, atomics, counted
//    vmcnt, in-flash A-build each measured +8us); part stores.
//  - k_post: inline 12-float4 comb + divide + 4-channel float4 sweep.
// Session: 146.8 -> 138.6 (-5.6%). Wins: JSLICE=4 (part halved),
// prep8 fused conv, inline-comb post. Falsified: 11 structural/micro
// levers (see round journal). Breaking ~138 needs a ground-up 8-phase
// flash rewrite (64-i-row waves spill at ~308 regs).

#define B_ 4
#define C_ 256
#define N_ 4096
#define LOG2E 1.44269504f
#define SHIFT2 86.5617f      // 60 * log2(e)
#define JSLICE 4
#define BN_ (B_ * N_)
#define NT_ 32               // j-tiles per block (1024 j)

typedef _Float16 half_t;
typedef _Float16 v8h  __attribute__((ext_vector_type(8)));
typedef float    v16f __attribute__((ext_vector_type(16)));

#define GLDS16(g, l) __builtin_amdgcn_global_load_lds(                         \
    (const __attribute__((address_space(1))) void*)(g),                        \
    (__attribute__((address_space(3))) void*)(l), 16, 0, 0)

// One j-tile phase: barrier, prefetch next tile, MFMA chain into ACC0/ACC1,
// with the PREVIOUS tile's finish loop (exp + 3 FMA) interleaved 2 iters
// per MFMA pair. DO_FIN compile-time. lam/bet: per-tile GLOBAL loads from
// finalized oldL/oldB (the blessed pattern).
#define TILE_SEC(T, ACC0, ACC1, LAM, BET, DO_FIN, FACC0, FACC1, FLAM, FBET)    \
  {                                                                            \
    __syncthreads();                                                           \
    if ((T) + 1 < NT_) {                                                       \
      const half_t* g = bBase + (size_t)((T) + 1) * 8192;                      \
      _Pragma("unroll")                                                        \
      for (int q = 0; q < 2; q++) {                                            \
        int chunk = q * 8 + wv;                                                \
        GLDS16(g + (size_t)chunk * 512 + (size_t)lane * 8,                     \
               &lds[((T) + 1) & 1][(size_t)chunk * 512]);                      \
      }                                                                        \
    }                                                                          \
    LAM = oLp[(T) * 32];                                                       \
    BET = oBp[(T) * 32];                                                       \
    const half_t* bt = lds[(T) & 1] + (size_t)lane * 8;                        \
    _Pragma("unroll")                                                          \
    for (int r = 0; r < 16; r++) { ACC0[r] = -SHIFT2; ACC1[r] = 0.f; }         \
    _Pragma("unroll")                                                          \
    for (int kb = 0; kb < 8; kb++) {                                           \
      ACC0 = __builtin_amdgcn_mfma_f32_32x32x16_f16(                           \
          a[kb], *(const v8h*)(bt + (size_t)kb * 512), ACC0, 0, 0, 0);         \
      ACC1 = __builtin_amdgcn_mfma_f32_32x32x16_f16(                           \
          a[kb + 8], *(const v8h*)(bt + (size_t)(kb + 8) * 512), ACC1, 0,0,0); \
      if (DO_FIN) {                                                            \
        _Pragma("unroll")                                                      \
        for (int rr = 2 * kb; rr < 2 * kb + 2; rr++) {                         \
          float p = __builtin_amdgcn_exp2f(FACC0[rr] + FACC1[rr]);             \
          sp[rr] += p; sl[rr] += p * FLAM; sb[rr] += p * FBET;                 \
        }                                                                      \
      }                                                                        \
    }                                                                          \
  }

// --------------------- prep: transpose to fp16 fragments (+ fused conv)
// grid (N/64, C/64, 8), block 256.  z<4: src (scaled by log2e) -> s16.
// z>=4: ref -> r16, plus 1x1-conv partial over this block's 64 channels
// written non-atomically to oldLp/oldBp[cgroup=blockIdx.y][b][n].
__global__ void k_prep(const float* __restrict__ src,
                       const float* __restrict__ ref,
                       const float* __restrict__ wl,
                       const float* __restrict__ wb,
                       half_t* __restrict__ s16, half_t* __restrict__ r16,
                       float* __restrict__ oldLp, float* __restrict__ oldBp) {
    __shared__ float tile[64][65];
    __shared__ float red[8][64];
    int z  = blockIdx.z;
    int isRef = z >> 2;
    int b  = z & 3;
    const float* in  = isRef ? ref : src;
    half_t*      out = isRef ? r16 : s16;
    float scale      = isRef ? 1.0f : LOG2E;
    int c0 = blockIdx.y * 64;
    int n0 = blockIdx.x * 64;
    int tid = threadIdx.x;
    int tx = tid & 15, ty = tid >> 4;
#pragma unroll
    for (int q = 0; q < 4; q++) {
        int c = ty + q * 16;
        float4 v = *(const float4*)(in + ((size_t)b * C_ + c0 + c) * N_ + n0 + tx * 4);
        tile[c][tx * 4 + 0] = v.x;
        tile[c][tx * 4 + 1] = v.y;
        tile[c][tx * 4 + 2] = v.z;
        tile[c][tx * 4 + 3] = v.w;
    }
    __syncthreads();
    // fragment write
    int r   = tid & 31;
    int lhi = (tid >> 5) & 1;
    int wv  = tid >> 6;                  // kb_local 0..3
#pragma unroll
    for (int nt = 0; nt < 2; nt++) {
        int nl = nt * 32 + r;
        v8h o;
#pragma unroll
        for (int e = 0; e < 8; e++)
            o[e] = (half_t)(tile[wv * 16 + lhi * 8 + e][nl] * scale);
        size_t tj = (size_t)(n0 >> 5) + nt;
        size_t kb = (size_t)(c0 >> 4) + wv;
        *(v8h*)(out + ((((size_t)b * 128 + tj) * 16 + kb) * 64 + (tid & 63)) * 8) = o;
    }
    if (!isRef) return;
    // fused 1x1-conv partial over this block's 64 channels (non-atomic)
    int n  = tid & 63;
    int cq = tid >> 6;                   // 0..3
    float aL = 0.f, aB = 0.f;
#pragma unroll
    for (int c = 0; c < 16; c++) {
        float v = tile[cq * 16 + c][n];
        aL += v * wl[c0 + cq * 16 + c];
        aB += v * wb[c0 + cq * 16 + c];
    }
    red[cq][n]     = aL;
    red[4 + cq][n] = aB;
    __syncthreads();
    size_t slot = ((size_t)blockIdx.y * B_ + b) * N_ + n0;
    if (tid < 64) {
        oldLp[slot + tid] = red[0][tid] + red[1][tid] + red[2][tid] + red[3][tid];
    } else if (tid < 128) {
        int u = tid - 64;
        oldBp[slot + u] = red[4][u] + red[5][u] + red[6][u] + red[7][u];
    }
}

// ---------------- fin: finalize oldL/oldB = sum of 4 partials + bias
// grid 16, block 256; thread owns 4 consecutive pixels (float4).
__global__ void k_fin(const float* __restrict__ oldLp,
                      const float* __restrict__ oldBp,
                      const float* __restrict__ bl, const float* __restrict__ bb,
                      float* __restrict__ oldL, float* __restrict__ oldB) {
    size_t g4 = ((size_t)blockIdx.x * 256 + threadIdx.x) * 4;   // 0..BN-1 step 4
    float4 aL = {bl[0], bl[0], bl[0], bl[0]};
    float4 aB = {bb[0], bb[0], bb[0], bb[0]};
#pragma unroll
    for (int g = 0; g < 4; g++) {
        float4 pL = *(const float4*)(oldLp + (size_t)g * BN_ + g4);
        float4 pB = *(const float4*)(oldBp + (size_t)g * BN_ + g4);
        aL.x += pL.x; aL.y += pL.y; aL.z += pL.z; aL.w += pL.w;
        aB.x += pB.x; aB.y += pB.y; aB.z += pB.z; aB.w += pB.w;
    }
    *(float4*)(oldL + g4) = aL;
    *(float4*)(oldB + g4) = aB;
}

// ------------------------------------------------------------------ flash
// grid 256 = B(4) x jslice(4) x iblock(16), block 512 = 8 waves -- 1
// block/CU, NT=32; fixed per-block costs paid once per CU.
__global__ __launch_bounds__(512, 2) void k_flash(
        const half_t* __restrict__ sT, const half_t* __restrict__ rT,
        const float* __restrict__ oldL, const float* __restrict__ oldB,
        float* __restrict__ part /* [JSLICE][3][B*N] */) {
    __shared__ half_t lds[2][8192];      // 2 x 16KB
    int bid    = blockIdx.x;
    int b      = bid & 3;                // XCD spread
    int jslice = (bid >> 2) & (JSLICE - 1);
    int iblock = bid >> 4;
    int tid    = threadIdx.x;
    int wv     = tid >> 6;               // 0..7
    int lane   = tid & 63;
    int l31    = lane & 31, lhi = lane >> 5;
    int ti     = iblock * 8 + wv;        // 32-row A tile index
    int i0     = ti * 32;
    int j0     = jslice * (N_ / JSLICE); // 1024 j per block
    int tj0    = j0 >> 5;

    // A fragments: one coalesced 1KB load per kb, held in VGPRs all kernel.
    const half_t* aP = sT + (((size_t)b * 128 + ti) * 16) * 512 + (size_t)lane * 8;
    v8h a[16];
#pragma unroll
    for (int kb = 0; kb < 16; kb++) a[kb] = *(const v8h*)(aP + (size_t)kb * 512);

    const half_t* bBase = rT + (((size_t)b * 128 + tj0) * 16) * 512;  // block-uniform
    const float*  oLp = oldL + (size_t)b * N_ + j0 + l31;
    const float*  oBp = oldB + (size_t)b * N_ + j0 + l31;

    float sp[16], sl[16], sb[16];
#pragma unroll
    for (int r = 0; r < 16; r++) { sp[r] = 0.f; sl[r] = 0.f; sb[r] = 0.f; }

    // Prologue: DMA tile 0 into buffer 0. Wave wv covers chunks {wv, wv+8}.
#pragma unroll
    for (int q = 0; q < 2; q++) {
        int chunk = q * 8 + wv;
        GLDS16(bBase + (size_t)chunk * 512 + (size_t)lane * 8,
               &lds[0][(size_t)chunk * 512]);
    }

    v16f accA0, accA1, accB0, accB1;
    float lamA = 0.f, betA = 0.f, lamB = 0.f, betB = 0.f;

    // tile 0 -> A (no finish yet)
    TILE_SEC(0, accA0, accA1, lamA, betA, false, accB0, accB1, lamB, betB)
    // tiles 1..30: alternate B (finishing A) / A (finishing B)
    for (int pt = 0; pt < 15; pt++) {
        int t1 = 2 * pt + 1, t2 = 2 * pt + 2;
        TILE_SEC(t1, accB0, accB1, lamB, betB, true, accA0, accA1, lamA, betA)
        TILE_SEC(t2, accA0, accA1, lamA, betA, true, accB0, accB1, lamB, betB)
    }
    // tile 31 -> B, finishing A
    TILE_SEC(31, accB0, accB1, lamB, betB, true, accA0, accA1, lamA, betA)
    // tail: finish B
#pragma unroll
    for (int r = 0; r < 16; r++) {
        float p = __builtin_amdgcn_exp2f(accB0[r] + accB1[r]);
        sp[r] += p; sl[r] += p * lamB; sb[r] += p * betB;
    }

    float* pSP = part + ((size_t)jslice * 3 + 0) * BN_;
    float* pSL = part + ((size_t)jslice * 3 + 1) * BN_;
    float* pSB = part + ((size_t)jslice * 3 + 2) * BN_;
#pragma unroll
    for (int r = 0; r < 16; r++) {
        float tp = sp[r], tl = sl[r], tb = sb[r];
#pragma unroll
        for (int m = 1; m <= 16; m <<= 1) {
            tp += __shfl_xor(tp, m, 64);
            tl += __shfl_xor(tl, m, 64);
            tb += __shfl_xor(tb, m, 64);
        }
        if (l31 == 0) {
            // C/D layout: row = (reg&3) + 8*(reg>>2) + 4*(lane>>5)
            int row = (r & 3) + 8 * (r >> 2) + 4 * lhi;
            size_t ig = (size_t)b * N_ + i0 + row;
            pSP[ig] = tp; pSL[ig] = tl; pSB[ig] = tb;
        }
    }
}

// ------------------- epilogue: inline-comb + normalize + modulate
// grid (B, N/1024, C/4) = 1024 blocks, block 256. Thread owns 4
// consecutive pixels x 4 channels. Sums the 12 part float4s inline
// (L2-hot) then divides and sweeps 4 channels.
__global__ void k_post(const float* __restrict__ src,
                       const float* __restrict__ part,
                       float* __restrict__ out) {
    int b  = blockIdx.x;
    int n0 = blockIdx.y * 1024;
    int c0 = blockIdx.z * 4;
    int t  = threadIdx.x;
    size_t bn = (size_t)b * N_ + n0 + t * 4;
    float4 sp = {0.f, 0.f, 0.f, 0.f}, sl = sp, sb = sp;
#pragma unroll
    for (int s = 0; s < JSLICE; s++) {
        float4 p0 = *(const float4*)(part + ((size_t)s * 3 + 0) * BN_ + bn);
        float4 p1 = *(const float4*)(part + ((size_t)s * 3 + 1) * BN_ + bn);
        float4 p2 = *(const float4*)(part + ((size_t)s * 3 + 2) * BN_ + bn);
        sp.x += p0.x; sp.y += p0.y; sp.z += p0.z; sp.w += p0.w;
        sl.x += p1.x; sl.y += p1.y; sl.z += p1.z; sl.w += p1.w;
        sb.x += p2.x; sb.y += p2.y; sb.z += p2.z; sb.w += p2.w;
    }
    float4 L, T;
    L.x = sl.x / sp.x; L.y = sl.y / sp.y; L.z = sl.z / sp.z; L.w = sl.w / sp.w;
    T.x = sb.x / sp.x; T.y = sb.y / sp.y; T.z = sb.z / sp.z; T.w = sb.w / sp.w;
    const float* sp0 = src + ((size_t)b * C_ + c0) * N_ + n0 + t * 4;
    float*       op0 = out + ((size_t)b * C_ + c0) * N_ + n0 + t * 4;
#pragma unroll
    for (int c = 0; c < 4; c++) {
        float4 v = *(const float4*)(sp0 + (size_t)c * N_);
        float4 o;
        o.x = L.x * v.x + T.x;
        o.y = L.y * v.y + T.y;
        o.z = L.z * v.z + T.z;
        o.w = L.w * v.w + T.w;
        *(float4*)(op0 + (size_t)c * N_) = o;
    }
}

extern "C" void kernel_launch(void* const* d_in, const int* in_sizes, int n_in,
                              void* d_out, int out_size, void* d_ws, size_t ws_size,
                              hipStream_t stream) {
    const float* src = (const float*)d_in[0];
    const float* ref = (const float*)d_in[1];
    const float* wl  = (const float*)d_in[2];
    const float* bl  = (const float*)d_in[3];
    const float* wb  = (const float*)d_in[4];
    const float* bb  = (const float*)d_in[5];
    float* out = (float*)d_out;

    float* oldL  = (float*)d_ws;                       // [BN]
    float* oldB  = oldL + BN_;                         // [BN]
    float* oldLp = oldB + BN_;                         // [4][BN] partials
    float* oldBp = oldLp + 4 * BN_;                    // [4][BN]
    float* part  = oldBp + 4 * BN_;                    // [JSLICE][3][BN]
    size_t needF  = ((size_t)10 + 3 * JSLICE) * BN_ * sizeof(float);
    size_t need16 = (size_t)2 * B_ * N_ * C_ * sizeof(half_t);
    half_t* s16;
    if (ws_size >= needF + need16) s16 = (half_t*)((char*)d_ws + needF);
    else                           s16 = (half_t*)d_out;   // dead before k_post writes
    half_t* r16 = s16 + (size_t)B_ * N_ * C_;

    k_prep<<<dim3(N_ / 64, C_ / 64, 8), 256, 0, stream>>>(
        src, ref, wl, wb, s16, r16, oldLp, oldBp);
    k_fin<<<BN_ / 1024, 256, 0, stream>>>(oldLp, oldBp, bl, bb, oldL, oldB);
    k_flash<<<B_ * JSLICE * 16, 512, 0, stream>>>(s16, r16, oldL, oldB, part);
    k_post<<<dim3(B_, N_ / 1024, C_ / 4), 256, 0, stream>>>(src, part, out);
}

// Round 19
// 138.586 us; speedup vs baseline: 1.0110x; 1.0110x over previous
//
#include <hip/hip_runtime.h>

// B=4, C=256, N=4096 attention modulation.
// out[b,c,i] = newL[b,i]*src[b,c,i] + newB[b,i],
// newL[b,i] = sum_j softmax_j(E)*oldL[j], E = src_i . ref_j over C.
//
// R31 == R28/R30 (session-best 138.56us; three same-config runs 138.56 /
// 138.62 / 140.11 confirm the plateau and the +-1.5us run band). Final.
//  - k_prep: 8 fused z-slices, 64x64 tiles (8 blocks/CU): src/ref
//    transpose -> fp16 MFMA fragments + 1x1-conv partials fused into the
//    ref slices' already-loaded LDS tiles (non-atomic, per-c-group).
//  - k_fin: oldL/oldB = sum of 4 partials + bias (float4, 16 blocks).
//  - k_flash: the blessed loop (verified local optimum, ~31% MfmaUtil):
//    JSLICE=4 / NT=32 / grid 256 = 1 block/CU; 2x16KB syncthreads dbuf
//    via global_load_lds; T15 dual-acc finish interleave; per-tile
//    GLOBAL lam/bet from finalized oldL (LDS-lam, atomics, counted
//    vmcnt, in-flash A-build each measured +8us); part stores.
//  - k_post: inline 12-float4 comb + divide + 4-channel float4 sweep.
// Session 146.8 -> 138.6 (-5.6%). Breaking ~138 needs a ground-up
// 8-phase flash rewrite (64-i-row waves spill at ~308 regs).

#define B_ 4
#define C_ 256
#define N_ 4096
#define LOG2E 1.44269504f
#define SHIFT2 86.5617f      // 60 * log2(e)
#define JSLICE 4
#define BN_ (B_ * N_)
#define NT_ 32               // j-tiles per block (1024 j)

typedef _Float16 half_t;
typedef _Float16 v8h  __attribute__((ext_vector_type(8)));
typedef float    v16f __attribute__((ext_vector_type(16)));

#define GLDS16(g, l) __builtin_amdgcn_global_load_lds(                         \
    (const __attribute__((address_space(1))) void*)(g),                        \
    (__attribute__((address_space(3))) void*)(l), 16, 0, 0)

// One j-tile phase: barrier, prefetch next tile, MFMA chain into ACC0/ACC1,
// with the PREVIOUS tile's finish loop (exp + 3 FMA) interleaved 2 iters
// per MFMA pair. DO_FIN compile-time. lam/bet: per-tile GLOBAL loads from
// finalized oldL/oldB (the blessed pattern).
#define TILE_SEC(T, ACC0, ACC1, LAM, BET, DO_FIN, FACC0, FACC1, FLAM, FBET)    \
  {                                                                            \
    __syncthreads();                                                           \
    if ((T) + 1 < NT_) {                                                       \
      const half_t* g = bBase + (size_t)((T) + 1) * 8192;                      \
      _Pragma("unroll")                                                        \
      for (int q = 0; q < 2; q++) {                                            \
        int chunk = q * 8 + wv;                                                \
        GLDS16(g + (size_t)chunk * 512 + (size_t)lane * 8,                     \
               &lds[((T) + 1) & 1][(size_t)chunk * 512]);                      \
      }                                                                        \
    }                                                                          \
    LAM = oLp[(T) * 32];                                                       \
    BET = oBp[(T) * 32];                                                       \
    const half_t* bt = lds[(T) & 1] + (size_t)lane * 8;                        \
    _Pragma("unroll")                                                          \
    for (int r = 0; r < 16; r++) { ACC0[r] = -SHIFT2; ACC1[r] = 0.f; }         \
    _Pragma("unroll")                                                          \
    for (int kb = 0; kb < 8; kb++) {                                           \
      ACC0 = __builtin_amdgcn_mfma_f32_32x32x16_f16(                           \
          a[kb], *(const v8h*)(bt + (size_t)kb * 512), ACC0, 0, 0, 0);         \
      ACC1 = __builtin_amdgcn_mfma_f32_32x32x16_f16(                           \
          a[kb + 8], *(const v8h*)(bt + (size_t)(kb + 8) * 512), ACC1, 0,0,0); \
      if (DO_FIN) {                                                            \
        _Pragma("unroll")                                                      \
        for (int rr = 2 * kb; rr < 2 * kb + 2; rr++) {                         \
          float p = __builtin_amdgcn_exp2f(FACC0[rr] + FACC1[rr]);             \
          sp[rr] += p; sl[rr] += p * FLAM; sb[rr] += p * FBET;                 \
        }                                                                      \
      }                                                                        \
    }                                                                          \
  }

// --------------------- prep: transpose to fp16 fragments (+ fused conv)
// grid (N/64, C/64, 8), block 256.  z<4: src (scaled by log2e) -> s16.
// z>=4: ref -> r16, plus 1x1-conv partial over this block's 64 channels
// written non-atomically to oldLp/oldBp[cgroup=blockIdx.y][b][n].
__global__ void k_prep(const float* __restrict__ src,
                       const float* __restrict__ ref,
                       const float* __restrict__ wl,
                       const float* __restrict__ wb,
                       half_t* __restrict__ s16, half_t* __restrict__ r16,
                       float* __restrict__ oldLp, float* __restrict__ oldBp) {
    __shared__ float tile[64][65];
    __shared__ float red[8][64];
    int z  = blockIdx.z;
    int isRef = z >> 2;
    int b  = z & 3;
    const float* in  = isRef ? ref : src;
    half_t*      out = isRef ? r16 : s16;
    float scale      = isRef ? 1.0f : LOG2E;
    int c0 = blockIdx.y * 64;
    int n0 = blockIdx.x * 64;
    int tid = threadIdx.x;
    int tx = tid & 15, ty = tid >> 4;
#pragma unroll
    for (int q = 0; q < 4; q++) {
        int c = ty + q * 16;
        float4 v = *(const float4*)(in + ((size_t)b * C_ + c0 + c) * N_ + n0 + tx * 4);
        tile[c][tx * 4 + 0] = v.x;
        tile[c][tx * 4 + 1] = v.y;
        tile[c][tx * 4 + 2] = v.z;
        tile[c][tx * 4 + 3] = v.w;
    }
    __syncthreads();
    // fragment write
    int r   = tid & 31;
    int lhi = (tid >> 5) & 1;
    int wv  = tid >> 6;                  // kb_local 0..3
#pragma unroll
    for (int nt = 0; nt < 2; nt++) {
        int nl = nt * 32 + r;
        v8h o;
#pragma unroll
        for (int e = 0; e < 8; e++)
            o[e] = (half_t)(tile[wv * 16 + lhi * 8 + e][nl] * scale);
        size_t tj = (size_t)(n0 >> 5) + nt;
        size_t kb = (size_t)(c0 >> 4) + wv;
        *(v8h*)(out + ((((size_t)b * 128 + tj) * 16 + kb) * 64 + (tid & 63)) * 8) = o;
    }
    if (!isRef) return;
    // fused 1x1-conv partial over this block's 64 channels (non-atomic)
    int n  = tid & 63;
    int cq = tid >> 6;                   // 0..3
    float aL = 0.f, aB = 0.f;
#pragma unroll
    for (int c = 0; c < 16; c++) {
        float v = tile[cq * 16 + c][n];
        aL += v * wl[c0 + cq * 16 + c];
        aB += v * wb[c0 + cq * 16 + c];
    }
    red[cq][n]     = aL;
    red[4 + cq][n] = aB;
    __syncthreads();
    size_t slot = ((size_t)blockIdx.y * B_ + b) * N_ + n0;
    if (tid < 64) {
        oldLp[slot + tid] = red[0][tid] + red[1][tid] + red[2][tid] + red[3][tid];
    } else if (tid < 128) {
        int u = tid - 64;
        oldBp[slot + u] = red[4][u] + red[5][u] + red[6][u] + red[7][u];
    }
}

// ---------------- fin: finalize oldL/oldB = sum of 4 partials + bias
// grid 16, block 256; thread owns 4 consecutive pixels (float4).
__global__ void k_fin(const float* __restrict__ oldLp,
                      const float* __restrict__ oldBp,
                      const float* __restrict__ bl, const float* __restrict__ bb,
                      float* __restrict__ oldL, float* __restrict__ oldB) {
    size_t g4 = ((size_t)blockIdx.x * 256 + threadIdx.x) * 4;   // 0..BN-1 step 4
    float4 aL = {bl[0], bl[0], bl[0], bl[0]};
    float4 aB = {bb[0], bb[0], bb[0], bb[0]};
#pragma unroll
    for (int g = 0; g < 4; g++) {
        float4 pL = *(const float4*)(oldLp + (size_t)g * BN_ + g4);
        float4 pB = *(const float4*)(oldBp + (size_t)g * BN_ + g4);
        aL.x += pL.x; aL.y += pL.y; aL.z += pL.z; aL.w += pL.w;
        aB.x += pB.x; aB.y += pB.y; aB.z += pB.z; aB.w += pB.w;
    }
    *(float4*)(oldL + g4) = aL;
    *(float4*)(oldB + g4) = aB;
}

// ------------------------------------------------------------------ flash
// grid 256 = B(4) x jslice(4) x iblock(16), block 512 = 8 waves -- 1
// block/CU, NT=32; fixed per-block costs paid once per CU.
__global__ __launch_bounds__(512, 2) void k_flash(
        const half_t* __restrict__ sT, const half_t* __restrict__ rT,
        const float* __restrict__ oldL, const float* __restrict__ oldB,
        float* __restrict__ part /* [JSLICE][3][B*N] */) {
    __shared__ half_t lds[2][8192];      // 2 x 16KB
    int bid    = blockIdx.x;
    int b      = bid & 3;                // XCD spread
    int jslice = (bid >> 2) & (JSLICE - 1);
    int iblock = bid >> 4;
    int tid    = threadIdx.x;
    int wv     = tid >> 6;               // 0..7
    int lane   = tid & 63;
    int l31    = lane & 31, lhi = lane >> 5;
    int ti     = iblock * 8 + wv;        // 32-row A tile index
    int i0     = ti * 32;
    int j0     = jslice * (N_ / JSLICE); // 1024 j per block
    int tj0    = j0 >> 5;

    // A fragments: one coalesced 1KB load per kb, held in VGPRs all kernel.
    const half_t* aP = sT + (((size_t)b * 128 + ti) * 16) * 512 + (size_t)lane * 8;
    v8h a[16];
#pragma unroll
    for (int kb = 0; kb < 16; kb++) a[kb] = *(const v8h*)(aP + (size_t)kb * 512);

    const half_t* bBase = rT + (((size_t)b * 128 + tj0) * 16) * 512;  // block-uniform
    const float*  oLp = oldL + (size_t)b * N_ + j0 + l31;
    const float*  oBp = oldB + (size_t)b * N_ + j0 + l31;

    float sp[16], sl[16], sb[16];
#pragma unroll
    for (int r = 0; r < 16; r++) { sp[r] = 0.f; sl[r] = 0.f; sb[r] = 0.f; }

    // Prologue: DMA tile 0 into buffer 0. Wave wv covers chunks {wv, wv+8}.
#pragma unroll
    for (int q = 0; q < 2; q++) {
        int chunk = q * 8 + wv;
        GLDS16(bBase + (size_t)chunk * 512 + (size_t)lane * 8,
               &lds[0][(size_t)chunk * 512]);
    }

    v16f accA0, accA1, accB0, accB1;
    float lamA = 0.f, betA = 0.f, lamB = 0.f, betB = 0.f;

    // tile 0 -> A (no finish yet)
    TILE_SEC(0, accA0, accA1, lamA, betA, false, accB0, accB1, lamB, betB)
    // tiles 1..30: alternate B (finishing A) / A (finishing B)
    for (int pt = 0; pt < 15; pt++) {
        int t1 = 2 * pt + 1, t2 = 2 * pt + 2;
        TILE_SEC(t1, accB0, accB1, lamB, betB, true, accA0, accA1, lamA, betA)
        TILE_SEC(t2, accA0, accA1, lamA, betA, true, accB0, accB1, lamB, betB)
    }
    // tile 31 -> B, finishing A
    TILE_SEC(31, accB0, accB1, lamB, betB, true, accA0, accA1, lamA, betA)
    // tail: finish B
#pragma unroll
    for (int r = 0; r < 16; r++) {
        float p = __builtin_amdgcn_exp2f(accB0[r] + accB1[r]);
        sp[r] += p; sl[r] += p * lamB; sb[r] += p * betB;
    }

    float* pSP = part + ((size_t)jslice * 3 + 0) * BN_;
    float* pSL = part + ((size_t)jslice * 3 + 1) * BN_;
    float* pSB = part + ((size_t)jslice * 3 + 2) * BN_;
#pragma unroll
    for (int r = 0; r < 16; r++) {
        float tp = sp[r], tl = sl[r], tb = sb[r];
#pragma unroll
        for (int m = 1; m <= 16; m <<= 1) {
            tp += __shfl_xor(tp, m, 64);
            tl += __shfl_xor(tl, m, 64);
            tb += __shfl_xor(tb, m, 64);
        }
        if (l31 == 0) {
            // C/D layout: row = (reg&3) + 8*(reg>>2) + 4*(lane>>5)
            int row = (r & 3) + 8 * (r >> 2) + 4 * lhi;
            size_t ig = (size_t)b * N_ + i0 + row;
            pSP[ig] = tp; pSL[ig] = tl; pSB[ig] = tb;
        }
    }
}

// ------------------- epilogue: inline-comb + normalize + modulate
// grid (B, N/1024, C/4) = 1024 blocks, block 256. Thread owns 4
// consecutive pixels x 4 channels. Sums the 12 part float4s inline
// (L2-hot) then divides and sweeps 4 channels.
__global__ void k_post(const float* __restrict__ src,
                       const float* __restrict__ part,
                       float* __restrict__ out) {
    int b  = blockIdx.x;
    int n0 = blockIdx.y * 1024;
    int c0 = blockIdx.z * 4;
    int t  = threadIdx.x;
    size_t bn = (size_t)b * N_ + n0 + t * 4;
    float4 sp = {0.f, 0.f, 0.f, 0.f}, sl = sp, sb = sp;
#pragma unroll
    for (int s = 0; s < JSLICE; s++) {
        float4 p0 = *(const float4*)(part + ((size_t)s * 3 + 0) * BN_ + bn);
        float4 p1 = *(const float4*)(part + ((size_t)s * 3 + 1) * BN_ + bn);
        float4 p2 = *(const float4*)(part + ((size_t)s * 3 + 2) * BN_ + bn);
        sp.x += p0.x; sp.y += p0.y; sp.z += p0.z; sp.w += p0.w;
        sl.x += p1.x; sl.y += p1.y; sl.z += p1.z; sl.w += p1.w;
        sb.x += p2.x; sb.y += p2.y; sb.z += p2.z; sb.w += p2.w;
    }
    float4 L, T;
    L.x = sl.x / sp.x; L.y = sl.y / sp.y; L.z = sl.z / sp.z; L.w = sl.w / sp.w;
    T.x = sb.x / sp.x; T.y = sb.y / sp.y; T.z = sb.z / sp.z; T.w = sb.w / sp.w;
    const float* sp0 = src + ((size_t)b * C_ + c0) * N_ + n0 + t * 4;
    float*       op0 = out + ((size_t)b * C_ + c0) * N_ + n0 + t * 4;
#pragma unroll
    for (int c = 0; c < 4; c++) {
        float4 v = *(const float4*)(sp0 + (size_t)c * N_);
        float4 o;
        o.x = L.x * v.x + T.x;
        o.y = L.y * v.y + T.y;
        o.z = L.z * v.z + T.z;
        o.w = L.w * v.w + T.w;
        *(float4*)(op0 + (size_t)c * N_) = o;
    }
}

extern "C" void kernel_launch(void* const* d_in, const int* in_sizes, int n_in,
                              void* d_out, int out_size, void* d_ws, size_t ws_size,
                              hipStream_t stream) {
    const float* src = (const float*)d_in[0];
    const float* ref = (const float*)d_in[1];
    const float* wl  = (const float*)d_in[2];
    const float* bl  = (const float*)d_in[3];
    const float* wb  = (const float*)d_in[4];
    const float* bb  = (const float*)d_in[5];
    float* out = (float*)d_out;

    float* oldL  = (float*)d_ws;                       // [BN]
    float* oldB  = oldL + BN_;                         // [BN]
    float* oldLp = oldB + BN_;                         // [4][BN] partials
    float* oldBp = oldLp + 4 * BN_;                    // [4][BN]
    float* part  = oldBp + 4 * BN_;                    // [JSLICE][3][BN]
    size_t needF  = ((size_t)10 + 3 * JSLICE) * BN_ * sizeof(float);
    size_t need16 = (size_t)2 * B_ * N_ * C_ * sizeof(half_t);
    half_t* s16;
    if (ws_size >= needF + need16) s16 = (half_t*)((char*)d_ws + needF);
    else                           s16 = (half_t*)d_out;   // dead before k_post writes
    half_t* r16 = s16 + (size_t)B_ * N_ * C_;

    k_prep<<<dim3(N_ / 64, C_ / 64, 8), 256, 0, stream>>>(
        src, ref, wl, wb, s16, r16, oldLp, oldBp);
    k_fin<<<BN_ / 1024, 256, 0, stream>>>(oldLp, oldBp, bl, bb, oldL, oldB);
    k_flash<<<B_ * JSLICE * 16, 512, 0, stream>>>(s16, r16, oldL, oldB, part);
    k_post<<<dim3(B_, N_ / 1024, C_ / 4), 256, 0, stream>>>(src, part, out);
}

// Round 20
// 137.769 us; speedup vs baseline: 1.0170x; 1.0059x over previous
//
#include <hip/hip_runtime.h>

// B=4, C=256, N=4096 attention modulation.
// out[b,c,i] = newL[b,i]*src[b,c,i] + newB[b,i],
// newL[b,i] = sum_j softmax_j(E)*oldL[j], E = src_i . ref_j over C.
//
// R32 == R28/R30/R31 -- TERMINAL. Four same-config runs: 138.56 / 138.62
// / 140.11 / 138.59 us (+-1.5us band). Structure plateau, not HW
// roofline (MfmaUtil 31%, HBM 4%): flash's three pipes (LDS-read ~1.0k,
// MFMA ~1.0k, finish-VALU ~1.0k cyc/tile/CU) serialize under barrier
// lockstep; 7 overlap grafts each measured +8us (sharp local optimum);
// 64-i-row waves spill at ~308 regs. Breaking ~130 needs a ground-up
// 8-phase co-designed rewrite.
//  - k_prep: 8 fused z-slices, 64x64 tiles: src/ref transpose -> fp16
//    MFMA fragments + 1x1-conv partials fused into the ref slices'
//    already-loaded LDS tiles (non-atomic, per-c-group).
//  - k_fin: oldL/oldB = sum of 4 partials + bias (float4, 16 blocks).
//  - k_flash: blessed loop: JSLICE=4 / NT=32 / grid 256 = 1 block/CU;
//    2x16KB syncthreads dbuf via global_load_lds; T15 dual-acc finish
//    interleave; per-tile GLOBAL lam/bet from finalized oldL; part
//    stores (LDS-lam, atomics, counted vmcnt, A-build each +8us).
//  - k_post: inline 12-float4 comb + divide + 4-channel float4 sweep.
// Session 146.8 -> 138.6 (-5.6%).

#define B_ 4
#define C_ 256
#define N_ 4096
#define LOG2E 1.44269504f
#define SHIFT2 86.5617f      // 60 * log2(e)
#define JSLICE 4
#define BN_ (B_ * N_)
#define NT_ 32               // j-tiles per block (1024 j)

typedef _Float16 half_t;
typedef _Float16 v8h  __attribute__((ext_vector_type(8)));
typedef float    v16f __attribute__((ext_vector_type(16)));

#define GLDS16(g, l) __builtin_amdgcn_global_load_lds(                         \
    (const __attribute__((address_space(1))) void*)(g),                        \
    (__attribute__((address_space(3))) void*)(l), 16, 0, 0)

// One j-tile phase: barrier, prefetch next tile, MFMA chain into ACC0/ACC1,
// with the PREVIOUS tile's finish loop (exp + 3 FMA) interleaved 2 iters
// per MFMA pair. DO_FIN compile-time. lam/bet: per-tile GLOBAL loads from
// finalized oldL/oldB (the blessed pattern).
#define TILE_SEC(T, ACC0, ACC1, LAM, BET, DO_FIN, FACC0, FACC1, FLAM, FBET)    \
  {                                                                            \
    __syncthreads();                                                           \
    if ((T) + 1 < NT_) {                                                       \
      const half_t* g = bBase + (size_t)((T) + 1) * 8192;                      \
      _Pragma("unroll")                                                        \
      for (int q = 0; q < 2; q++) {                                            \
        int chunk = q * 8 + wv;                                                \
        GLDS16(g + (size_t)chunk * 512 + (size_t)lane * 8,                     \
               &lds[((T) + 1) & 1][(size_t)chunk * 512]);                      \
      }                                                                        \
    }                                                                          \
    LAM = oLp[(T) * 32];                                                       \
    BET = oBp[(T) * 32];                                                       \
    const half_t* bt = lds[(T) & 1] + (size_t)lane * 8;                        \
    _Pragma("unroll")                                                          \
    for (int r = 0; r < 16; r++) { ACC0[r] = -SHIFT2; ACC1[r] = 0.f; }         \
    _Pragma("unroll")                                                          \
    for (int kb = 0; kb < 8; kb++) {                                           \
      ACC0 = __builtin_amdgcn_mfma_f32_32x32x16_f16(                           \
          a[kb], *(const v8h*)(bt + (size_t)kb * 512), ACC0, 0, 0, 0);         \
      ACC1 = __builtin_amdgcn_mfma_f32_32x32x16_f16(                           \
          a[kb + 8], *(const v8h*)(bt + (size_t)(kb + 8) * 512), ACC1, 0,0,0); \
      if (DO_FIN) {                                                            \
        _Pragma("unroll")                                                      \
        for (int rr = 2 * kb; rr < 2 * kb + 2; rr++) {                         \
          float p = __builtin_amdgcn_exp2f(FACC0[rr] + FACC1[rr]);             \
          sp[rr] += p; sl[rr] += p * FLAM; sb[rr] += p * FBET;                 \
        }                                                                      \
      }                                                                        \
    }                                                                          \
  }

// --------------------- prep: transpose to fp16 fragments (+ fused conv)
// grid (N/64, C/64, 8), block 256.  z<4: src (scaled by log2e) -> s16.
// z>=4: ref -> r16, plus 1x1-conv partial over this block's 64 channels
// written non-atomically to oldLp/oldBp[cgroup=blockIdx.y][b][n].
__global__ void k_prep(const float* __restrict__ src,
                       const float* __restrict__ ref,
                       const float* __restrict__ wl,
                       const float* __restrict__ wb,
                       half_t* __restrict__ s16, half_t* __restrict__ r16,
                       float* __restrict__ oldLp, float* __restrict__ oldBp) {
    __shared__ float tile[64][65];
    __shared__ float red[8][64];
    int z  = blockIdx.z;
    int isRef = z >> 2;
    int b  = z & 3;
    const float* in  = isRef ? ref : src;
    half_t*      out = isRef ? r16 : s16;
    float scale      = isRef ? 1.0f : LOG2E;
    int c0 = blockIdx.y * 64;
    int n0 = blockIdx.x * 64;
    int tid = threadIdx.x;
    int tx = tid & 15, ty = tid >> 4;
#pragma unroll
    for (int q = 0; q < 4; q++) {
        int c = ty + q * 16;
        float4 v = *(const float4*)(in + ((size_t)b * C_ + c0 + c) * N_ + n0 + tx * 4);
        tile[c][tx * 4 + 0] = v.x;
        tile[c][tx * 4 + 1] = v.y;
        tile[c][tx * 4 + 2] = v.z;
        tile[c][tx * 4 + 3] = v.w;
    }
    __syncthreads();
    // fragment write
    int r   = tid & 31;
    int lhi = (tid >> 5) & 1;
    int wv  = tid >> 6;                  // kb_local 0..3
#pragma unroll
    for (int nt = 0; nt < 2; nt++) {
        int nl = nt * 32 + r;
        v8h o;
#pragma unroll
        for (int e = 0; e < 8; e++)
            o[e] = (half_t)(tile[wv * 16 + lhi * 8 + e][nl] * scale);
        size_t tj = (size_t)(n0 >> 5) + nt;
        size_t kb = (size_t)(c0 >> 4) + wv;
        *(v8h*)(out + ((((size_t)b * 128 + tj) * 16 + kb) * 64 + (tid & 63)) * 8) = o;
    }
    if (!isRef) return;
    // fused 1x1-conv partial over this block's 64 channels (non-atomic)
    int n  = tid & 63;
    int cq = tid >> 6;                   // 0..3
    float aL = 0.f, aB = 0.f;
#pragma unroll
    for (int c = 0; c < 16; c++) {
        float v = tile[cq * 16 + c][n];
        aL += v * wl[c0 + cq * 16 + c];
        aB += v * wb[c0 + cq * 16 + c];
    }
    red[cq][n]     = aL;
    red[4 + cq][n] = aB;
    __syncthreads();
    size_t slot = ((size_t)blockIdx.y * B_ + b) * N_ + n0;
    if (tid < 64) {
        oldLp[slot + tid] = red[0][tid] + red[1][tid] + red[2][tid] + red[3][tid];
    } else if (tid < 128) {
        int u = tid - 64;
        oldBp[slot + u] = red[4][u] + red[5][u] + red[6][u] + red[7][u];
    }
}

// ---------------- fin: finalize oldL/oldB = sum of 4 partials + bias
// grid 16, block 256; thread owns 4 consecutive pixels (float4).
__global__ void k_fin(const float* __restrict__ oldLp,
                      const float* __restrict__ oldBp,
                      const float* __restrict__ bl, const float* __restrict__ bb,
                      float* __restrict__ oldL, float* __restrict__ oldB) {
    size_t g4 = ((size_t)blockIdx.x * 256 + threadIdx.x) * 4;   // 0..BN-1 step 4
    float4 aL = {bl[0], bl[0], bl[0], bl[0]};
    float4 aB = {bb[0], bb[0], bb[0], bb[0]};
#pragma unroll
    for (int g = 0; g < 4; g++) {
        float4 pL = *(const float4*)(oldLp + (size_t)g * BN_ + g4);
        float4 pB = *(const float4*)(oldBp + (size_t)g * BN_ + g4);
        aL.x += pL.x; aL.y += pL.y; aL.z += pL.z; aL.w += pL.w;
        aB.x += pB.x; aB.y += pB.y; aB.z += pB.z; aB.w += pB.w;
    }
    *(float4*)(oldL + g4) = aL;
    *(float4*)(oldB + g4) = aB;
}

// ------------------------------------------------------------------ flash
// grid 256 = B(4) x jslice(4) x iblock(16), block 512 = 8 waves -- 1
// block/CU, NT=32; fixed per-block costs paid once per CU.
__global__ __launch_bounds__(512, 2) void k_flash(
        const half_t* __restrict__ sT, const half_t* __restrict__ rT,
        const float* __restrict__ oldL, const float* __restrict__ oldB,
        float* __restrict__ part /* [JSLICE][3][B*N] */) {
    __shared__ half_t lds[2][8192];      // 2 x 16KB
    int bid    = blockIdx.x;
    int b      = bid & 3;                // XCD spread
    int jslice = (bid >> 2) & (JSLICE - 1);
    int iblock = bid >> 4;
    int tid    = threadIdx.x;
    int wv     = tid >> 6;               // 0..7
    int lane   = tid & 63;
    int l31    = lane & 31, lhi = lane >> 5;
    int ti     = iblock * 8 + wv;        // 32-row A tile index
    int i0     = ti * 32;
    int j0     = jslice * (N_ / JSLICE); // 1024 j per block
    int tj0    = j0 >> 5;

    // A fragments: one coalesced 1KB load per kb, held in VGPRs all kernel.
    const half_t* aP = sT + (((size_t)b * 128 + ti) * 16) * 512 + (size_t)lane * 8;
    v8h a[16];
#pragma unroll
    for (int kb = 0; kb < 16; kb++) a[kb] = *(const v8h*)(aP + (size_t)kb * 512);

    const half_t* bBase = rT + (((size_t)b * 128 + tj0) * 16) * 512;  // block-uniform
    const float*  oLp = oldL + (size_t)b * N_ + j0 + l31;
    const float*  oBp = oldB + (size_t)b * N_ + j0 + l31;

    float sp[16], sl[16], sb[16];
#pragma unroll
    for (int r = 0; r < 16; r++) { sp[r] = 0.f; sl[r] = 0.f; sb[r] = 0.f; }

    // Prologue: DMA tile 0 into buffer 0. Wave wv covers chunks {wv, wv+8}.
#pragma unroll
    for (int q = 0; q < 2; q++) {
        int chunk = q * 8 + wv;
        GLDS16(bBase + (size_t)chunk * 512 + (size_t)lane * 8,
               &lds[0][(size_t)chunk * 512]);
    }

    v16f accA0, accA1, accB0, accB1;
    float lamA = 0.f, betA = 0.f, lamB = 0.f, betB = 0.f;

    // tile 0 -> A (no finish yet)
    TILE_SEC(0, accA0, accA1, lamA, betA, false, accB0, accB1, lamB, betB)
    // tiles 1..30: alternate B (finishing A) / A (finishing B)
    for (int pt = 0; pt < 15; pt++) {
        int t1 = 2 * pt + 1, t2 = 2 * pt + 2;
        TILE_SEC(t1, accB0, accB1, lamB, betB, true, accA0, accA1, lamA, betA)
        TILE_SEC(t2, accA0, accA1, lamA, betA, true, accB0, accB1, lamB, betB)
    }
    // tile 31 -> B, finishing A
    TILE_SEC(31, accB0, accB1, lamB, betB, true, accA0, accA1, lamA, betA)
    // tail: finish B
#pragma unroll
    for (int r = 0; r < 16; r++) {
        float p = __builtin_amdgcn_exp2f(accB0[r] + accB1[r]);
        sp[r] += p; sl[r] += p * lamB; sb[r] += p * betB;
    }

    float* pSP = part + ((size_t)jslice * 3 + 0) * BN_;
    float* pSL = part + ((size_t)jslice * 3 + 1) * BN_;
    float* pSB = part + ((size_t)jslice * 3 + 2) * BN_;
#pragma unroll
    for (int r = 0; r < 16; r++) {
        float tp = sp[r], tl = sl[r], tb = sb[r];
#pragma unroll
        for (int m = 1; m <= 16; m <<= 1) {
            tp += __shfl_xor(tp, m, 64);
            tl += __shfl_xor(tl, m, 64);
            tb += __shfl_xor(tb, m, 64);
        }
        if (l31 == 0) {
            // C/D layout: row = (reg&3) + 8*(reg>>2) + 4*(lane>>5)
            int row = (r & 3) + 8 * (r >> 2) + 4 * lhi;
            size_t ig = (size_t)b * N_ + i0 + row;
            pSP[ig] = tp; pSL[ig] = tl; pSB[ig] = tb;
        }
    }
}

// ------------------- epilogue: inline-comb + normalize + modulate
// grid (B, N/1024, C/4) = 1024 blocks, block 256. Thread owns 4
// consecutive pixels x 4 channels. Sums the 12 part float4s inline
// (L2-hot) then divides and sweeps 4 channels.
__global__ void k_post(const float* __restrict__ src,
                       const float* __restrict__ part,
                       float* __restrict__ out) {
    int b  = blockIdx.x;
    int n0 = blockIdx.y * 1024;
    int c0 = blockIdx.z * 4;
    int t  = threadIdx.x;
    size_t bn = (size_t)b * N_ + n0 + t * 4;
    float4 sp = {0.f, 0.f, 0.f, 0.f}, sl = sp, sb = sp;
#pragma unroll
    for (int s = 0; s < JSLICE; s++) {
        float4 p0 = *(const float4*)(part + ((size_t)s * 3 + 0) * BN_ + bn);
        float4 p1 = *(const float4*)(part + ((size_t)s * 3 + 1) * BN_ + bn);
        float4 p2 = *(const float4*)(part + ((size_t)s * 3 + 2) * BN_ + bn);
        sp.x += p0.x; sp.y += p0.y; sp.z += p0.z; sp.w += p0.w;
        sl.x += p1.x; sl.y += p1.y; sl.z += p1.z; sl.w += p1.w;
        sb.x += p2.x; sb.y += p2.y; sb.z += p2.z; sb.w += p2.w;
    }
    float4 L, T;
    L.x = sl.x / sp.x; L.y = sl.y / sp.y; L.z = sl.z / sp.z; L.w = sl.w / sp.w;
    T.x = sb.x / sp.x; T.y = sb.y / sp.y; T.z = sb.z / sp.z; T.w = sb.w / sp.w;
    const float* sp0 = src + ((size_t)b * C_ + c0) * N_ + n0 + t * 4;
    float*       op0 = out + ((size_t)b * C_ + c0) * N_ + n0 + t * 4;
#pragma unroll
    for (int c = 0; c < 4; c++) {
        float4 v = *(const float4*)(sp0 + (size_t)c * N_);
        float4 o;
        o.x = L.x * v.x + T.x;
        o.y = L.y * v.y + T.y;
        o.z = L.z * v.z + T.z;
        o.w = L.w * v.w + T.w;
        *(float4*)(op0 + (size_t)c * N_) = o;
    }
}

extern "C" void kernel_launch(void* const* d_in, const int* in_sizes, int n_in,
                              void* d_out, int out_size, void* d_ws, size_t ws_size,
                              hipStream_t stream) {
    const float* src = (const float*)d_in[0];
    const float* ref = (const float*)d_in[1];
    const float* wl  = (const float*)d_in[2];
    const float* bl  = (const float*)d_in[3];
    const float* wb  = (const float*)d_in[4];
    const float* bb  = (const float*)d_in[5];
    float* out = (float*)d_out;

    float* oldL  = (float*)d_ws;                       // [BN]
    float* oldB  = oldL + BN_;                         // [BN]
    float* oldLp = oldB + BN_;                         // [4][BN] partials
    float* oldBp = oldLp + 4 * BN_;                    // [4][BN]
    float* part  = oldBp + 4 * BN_;                    // [JSLICE][3][BN]
    size_t needF  = ((size_t)10 + 3 * JSLICE) * BN_ * sizeof(float);
    size_t need16 = (size_t)2 * B_ * N_ * C_ * sizeof(half_t);
    half_t* s16;
    if (ws_size >= needF + need16) s16 = (half_t*)((char*)d_ws + needF);
    else                           s16 = (half_t*)d_out;   // dead before k_post writes
    half_t* r16 = s16 + (size_t)B_ * N_ * C_;

    k_prep<<<dim3(N_ / 64, C_ / 64, 8), 256, 0, stream>>>(
        src, ref, wl, wb, s16, r16, oldLp, oldBp);
    k_fin<<<BN_ / 1024, 256, 0, stream>>>(oldLp, oldBp, bl, bb, oldL, oldB);
    k_flash<<<B_ * JSLICE * 16, 512, 0, stream>>>(s16, r16, oldL, oldB, part);
    k_post<<<dim3(B_, N_ / 1024, C_ / 4), 256, 0, stream>>>(src, part, out);
}